// Round 11
// baseline (15398.451 us; speedup 1.0000x reference)
//
#include <hip/hip_runtime.h>

#define Bsz 64
#define Tsz 1024
#define Vsz 100
#define Esz 100
#define Hsz 1024
#define G4  4096

typedef __attribute__((ext_vector_type(8))) short short8;
typedef __attribute__((ext_vector_type(4))) float f32x4;
typedef __attribute__((ext_vector_type(4))) int   i32x4;
typedef unsigned int u32;

// ---------- helpers ----------
__device__ __forceinline__ unsigned short f2bf(float f) {
  union { float f; u32 u; } v; v.f = f;
  u32 u = v.u + 0x7fffu + ((v.u >> 16) & 1u);   // RNE
  return (unsigned short)(u >> 16);
}
__device__ __forceinline__ float sigm(float x) { return 1.f / (1.f + __expf(-x)); }
__device__ __forceinline__ float tanh_(float x) {
  float e = __expf(2.f * x);
  return 1.f - 2.f / (e + 1.f);
}

// device-scope (LLC) coherent ops — proven rounds 2/3/7/8
__device__ __forceinline__ void store_s32_coh(int* p, int v) {
  asm volatile("global_store_dword %0, %1, off sc0 sc1" :: "v"(p), "v"(v) : "memory");
}
__device__ __forceinline__ int load_s32_coh(const int* p) {
  int v;
  asm volatile("global_load_dword %0, %1, off sc0 sc1\n\ts_waitcnt vmcnt(0)"
               : "=v"(v) : "v"(p) : "memory");
  return v;
}
__device__ __forceinline__ void store_x4_coh(void* p, i32x4 v) {
  asm volatile("global_store_dwordx4 %0, %1, off sc0 sc1" :: "v"(p), "v"(v) : "memory");
}
__device__ __forceinline__ void drain_vmem() {
  asm volatile("s_waitcnt vmcnt(0)" ::: "memory");
}

// ---------- kernel A: gate lookup table  table[v][p] = emb[v]@Wih[orig(p)] + bih + bhh ----------
// permuted col p = wg*128 + g*32 + d  ->  orig = g*1024 + wg*32 + d   (wg 0..31, g 0..3, d 0..31)
__global__ __launch_bounds__(256) void k_table(const float* __restrict__ emb,
                                               const float* __restrict__ Wih,
                                               const float* __restrict__ bih,
                                               const float* __restrict__ bhh,
                                               float* __restrict__ table) {
  __shared__ float es[Vsz * Esz];
  int tid = threadIdx.x;
  for (int i = tid; i < Vsz * Esz; i += 256) es[i] = emb[i];
  __syncthreads();
  int p = blockIdx.x * 256 + tid;          // 0..4095
  int wg = p >> 7;
  int g = (p >> 5) & 3;
  int d = p & 31;
  int orig = g * Hsz + wg * 32 + d;
  float w[Esz];
  #pragma unroll
  for (int e = 0; e < Esz; ++e) w[e] = Wih[(size_t)orig * Esz + e];
  float bias = bih[orig] + bhh[orig];
  for (int v = 0; v < Vsz; ++v) {
    float acc = bias;
    #pragma unroll
    for (int e = 0; e < Esz; ++e) acc += es[v * Esz + e] * w[e];
    table[(size_t)v * G4 + p] = acc;
  }
}

// ---------- kernel W: WdecT[k][v] (pad v to 112) + zero sync flags ----------
__global__ __launch_bounds__(256) void k_wdecT(const float* __restrict__ Wdec,
                                               float* __restrict__ WdecT,
                                               int* __restrict__ flags) {  // 512 ints
  if (blockIdx.x == 0) {
    for (int i = threadIdx.x; i < 512; i += 256) store_s32_coh(flags + i, 0);
  }
  int idx = blockIdx.x * 256 + threadIdx.x;   // k*112+v
  if (idx >= 1024 * 112) return;
  int k = idx / 112, v = idx - k * 112;
  WdecT[idx] = (v < Vsz) ? Wdec[(size_t)v * Hsz + k] : 0.f;
}

// ---------- zero tail: out rows with t >= group Lmax ----------
__global__ __launch_bounds__(256) void k_zero_tail(const int* __restrict__ lens,
                                                   float* __restrict__ out_o) {
  int b = blockIdx.x;                       // 0..63
  int Lmax = lens[(b >> 3) << 3];
  f32x4 z = {0.f, 0.f, 0.f, 0.f};
  for (int t = Lmax; t < Tsz; ++t) {
    f32x4* p = (f32x4*)(out_o + ((size_t)b * Tsz + t) * Hsz);
    p[threadIdx.x] = z;                     // 256 x 4 floats = 1024
  }
}

// ---------- persistent LSTM: seqlock handoff + per-chunk dataflow consumption ----------
// 256 WGs x 256 thr, plain launch. 8 groups (bid&7) of 32 WGs; group owns rows grp*8..+7;
// WG rank wg owns dims wg*32..+31 (all 4 gates; B in regs). h double-buffered, tag bit in
// every dword LSB (=(t>>1)&1). Producers: tagged sc0sc1 dwordx4 (store IS the release).
// Consumers: chunk c (dims 32c..+32 == MFMA k-step c) polled per-piece (64B/lane) by the
// owning wave; staged pieces drop out of later rounds; chunks are MFMA'd in arrival order
// (LDS rgen[c]==t scan + ballot). Own chunk direct-staged from registers during act (no
// global RT). One __syncthreads per step (before act). All spins budget-bounded.
__global__ __launch_bounds__(256, 1) void k_lstm(const int* __restrict__ chars,
                                                 const int* __restrict__ lens,
                                                 const float* __restrict__ Whh,
                                                 const float* __restrict__ table,
                                                 unsigned short* __restrict__ hbf, // [2][64][1024]
                                                 int* __restrict__ flags,          // [8][64] (32 used)
                                                 float* __restrict__ dout) {
  const int tid = threadIdx.x;
  const int lane = tid & 63;
  const int wave = tid >> 6;                 // 0..3 (= gate index for MFMA tiles)
  const int bid = blockIdx.x;
  const int grp = bid & 7;                   // group
  const int wg  = bid >> 3;                  // 0..31 rank in group
  const int wgdim0 = wg * 32;

  float* out_o  = dout;
  float* out_hn = dout + 67108864;
  float* out_cn = dout + 67174400;

  int* gflags = flags + grp * 64;            // 32 packed flags (128B)
  int* myflag = gflags + wg;

  __shared__ unsigned short hstage[2][16 * 1024];  // 64KB, double-buffered; rows 8-15 zero
  __shared__ float gatex[4][8][33];                // [gate][row][dim] 4.2KB
  __shared__ int cnt[2][32];                       // staged 16B-units per chunk (thresh 32)
  __shared__ volatile int rgen[32];                // chunk ready generation (== t)

  // ---- roles ----
  const int r_act = tid >> 5;                // act/producer row 0..7
  const int d_act = tid & 31;                // dim within WG slice
  const int row_g = grp * 8 + r_act;
  const int Lr = lens[row_g];
  const int Lmax = lens[grp * 8];            // sorted descending -> group max
  const int dim = wgdim0 + d_act;
  const int packer = ((d_act & 7) == 0);
  // dataflow piece: wave owns chunks wave*8..+7; lane -> (chunk, row)
  const int pchunk = wave * 8 + (lane >> 3);
  const int prow = lane & 7;
  const int prow_g = grp * 8 + prow;
  float cs = 0.f;
  u32 hlast = 0;
  int budget = 1 << 20;                      // cumulative spin budget (anti-hang)

  // ---- init control state ----
  if (tid < 32) { cnt[0][tid] = 0; cnt[1][tid] = 0; rgen[tid] = -1; }

  // ---- init: tag both global buffers (own slice), replay-safe ----
  if (packer) {
    char* c0 = (char*)hbf + (size_t)row_g * 2048 + (size_t)dim * 2;
    i32x4 z0 = {0, 0, 0, 0};
    i32x4 z1 = {0x00010001, 0x00010001, 0x00010001, 0x00010001};
    store_x4_coh(c0, z0);
    store_x4_coh(c0 + 131072, z1);
  }
  drain_vmem();
  __syncthreads();
  if (tid == 0) store_s32_coh(myflag, 1);

  // ---- one-time heavy work (overlaps other WGs' init) ----
  short8 Bf[32][2];
  {
    const int col = lane & 15;
    const int ko = (lane >> 4) * 8;
    #pragma unroll
    for (int kk = 0; kk < 32; ++kk) {
      #pragma unroll
      for (int hh = 0; hh < 2; ++hh) {
        int orig = wave * Hsz + wgdim0 + hh * 16 + col;
        const float* src = Whh + (size_t)orig * Hsz + kk * 32 + ko;
        f32x4 f0 = *(const f32x4*)(src);
        f32x4 f1 = *(const f32x4*)(src + 4);
        short8 bb;
        bb[0] = (short)f2bf(f0[0]); bb[1] = (short)f2bf(f0[1]);
        bb[2] = (short)f2bf(f0[2]); bb[3] = (short)f2bf(f0[3]);
        bb[4] = (short)f2bf(f1[0]); bb[5] = (short)f2bf(f1[1]);
        bb[6] = (short)f2bf(f1[2]); bb[7] = (short)f2bf(f1[3]);
        Bf[kk][hh] = bb;
      }
    }
  }
  {   // zero hstage rows 8..15 in BOTH buffers (MFMA upper rows stay zero)
    f32x4 z = {0.f, 0.f, 0.f, 0.f};
    f32x4* h0 = (f32x4*)(hstage[0] + 8 * 1024);
    f32x4* h1 = (f32x4*)(hstage[1] + 8 * 1024);
    for (int i = tid; i < 1024; i += 256) { h0[i] = z; h1[i] = z; }
  }

  // ---- init barrier (device scope, bounded) ----
  if (wave == 0) {
    const int* fp = gflags + (lane & 31);
    for (;;) {
      int f = load_s32_coh(fp);
      if (__all(f >= 1)) break;
      if (--budget < 0) break;
    }
  }
  __syncthreads();

  for (int t = 0; t < Tsz; ++t) {
    if (Lmax <= t) break;                    // uniform across group
    const u32 tgR = (u32)((t >> 1) & 1);
    const u32 tgW = (u32)(((t + 1) >> 1) & 1);
    const char* bufR = (const char*)hbf + (size_t)(t & 1) * 131072;
    char* bufW = (char*)hbf + (size_t)((t & 1) ^ 1) * 131072;
    const char* hsR = (const char*)hstage[t & 1];
    unsigned short* hsW = hstage[(t & 1) ^ 1];   // direct-stage target (h(t+1))

    const int active = (Lr > t);
    int ch = active ? chars[(size_t)row_g * Tsz + t] : 0;

    // gate-table gather (cached; overlaps the dataflow loop)
    float tv0 = 0.f, tv1 = 0.f, tv2 = 0.f, tv3 = 0.f;
    if (active) {
      const float* tb = table + (size_t)ch * G4 + wg * 128 + d_act;
      tv0 = tb[0]; tv1 = tb[32]; tv2 = tb[64]; tv3 = tb[96];
    }

    // ---- dataflow: poll pieces + stage + MFMA chunks in arrival order ----
    f32x4 a00 = {0.f,0.f,0.f,0.f}, a01 = {0.f,0.f,0.f,0.f};
    f32x4 a10 = {0.f,0.f,0.f,0.f}, a11 = {0.f,0.f,0.f,0.f};
    {
      bool pend = (t == 0) ? true : (pchunk != wg);   // own chunk direct-staged for t>0
      const char* q = bufR + (size_t)prow_g * 2048 + 64 * pchunk;
      char* stg = (char*)hstage[t & 1] + prow * 2048;
      const int swzP = prow << 4;
      const int yb = 64 * pchunk;
      const int arow = lane & 15;
      const int aswz = (arow & 7) << 4;
      const int axb = (lane >> 4) << 4;
      u32 done = 0;
      for (;;) {
        if (__any(pend ? 1 : 0)) {
          if (pend) {
            i32x4 c0, c1, c2, c3;
            asm volatile(
              "global_load_dwordx4 %0, %4, off sc0 sc1\n\t"
              "global_load_dwordx4 %1, %5, off sc0 sc1\n\t"
              "global_load_dwordx4 %2, %6, off sc0 sc1\n\t"
              "global_load_dwordx4 %3, %7, off sc0 sc1\n\t"
              "s_waitcnt vmcnt(0)"
              : "=v"(c0), "=v"(c1), "=v"(c2), "=v"(c3)
              : "v"(q), "v"(q + 16), "v"(q + 32), "v"(q + 48)
              : "memory");
            u32 orb = (u32)(c0[0] | c0[1] | c0[2] | c0[3] |
                            c1[0] | c1[1] | c1[2] | c1[3] |
                            c2[0] | c2[1] | c2[2] | c2[3] |
                            c3[0] | c3[1] | c3[2] | c3[3]);
            u32 anb = (u32)(c0[0] & c0[1] & c0[2] & c0[3] &
                            c1[0] & c1[1] & c1[2] & c1[3] &
                            c2[0] & c2[1] & c2[2] & c2[3] &
                            c3[0] & c3[1] & c3[2] & c3[3]);
            u32 bad = tgR ? ((anb & 1u) ^ 1u) : (orb & 1u);
            if (!bad) {
              *(i32x4*)(stg + ((yb     ) ^ swzP)) = c0;
              *(i32x4*)(stg + ((yb + 16) ^ swzP)) = c1;
              *(i32x4*)(stg + ((yb + 32) ^ swzP)) = c2;
              *(i32x4*)(stg + ((yb + 48) ^ swzP)) = c3;
              asm volatile("s_waitcnt lgkmcnt(0)" ::: "memory");
              int old = atomicAdd(&cnt[t & 1][pchunk], 4);
              if (old == 28) { rgen[pchunk] = t; cnt[t & 1][pchunk] = 0; }
              pend = false;
            }
          }
        }
        // ready scan (uniform): chunks with rgen==t not yet consumed
        int g = rgen[lane & 31];
        unsigned long long bal = __ballot((lane < 32) && (g == t));
        u32 todo = ((u32)bal) & ~done;
        while (todo) {
          int c = __builtin_ctz(todo);
          todo &= todo - 1;
          int off = ((c << 6) | axb) ^ aswz;
          short8 av = *(const short8*)(hsR + arow * 2048 + off);
          if (c & 1) {
            a01 = __builtin_amdgcn_mfma_f32_16x16x32_bf16(av, Bf[c][0], a01, 0, 0, 0);
            a11 = __builtin_amdgcn_mfma_f32_16x16x32_bf16(av, Bf[c][1], a11, 0, 0, 0);
          } else {
            a00 = __builtin_amdgcn_mfma_f32_16x16x32_bf16(av, Bf[c][0], a00, 0, 0, 0);
            a10 = __builtin_amdgcn_mfma_f32_16x16x32_bf16(av, Bf[c][1], a10, 0, 0, 0);
          }
          done |= 1u << c;
        }
        if (done == 0xFFFFFFFFu) break;
        if (--budget < 0) break;
      }
    }
    if (lane < 32) {           // rows 0..7 only
      f32x4 v0 = a00 + a01;    // dims 0..15
      f32x4 v1 = a10 + a11;    // dims 16..31
      int col = lane & 15;
      int r0 = (lane >> 4) * 4;
      #pragma unroll
      for (int i = 0; i < 4; ++i) {
        gatex[wave][r0 + i][col]      = v0[i];
        gatex[wave][r0 + i][16 + col] = v1[i];
      }
    }
    __syncthreads();           // all gates in gatex; also fences hstage/rgen reuse

    // ---- activation + state; release = tagged store; own chunk direct-staged ----
    float hn = 0.f, cn = 0.f;
    if (active) {
      float gi = gatex[0][r_act][d_act] + tv0;
      float gf = gatex[1][r_act][d_act] + tv1;
      float gg = gatex[2][r_act][d_act] + tv2;
      float go = gatex[3][r_act][d_act] + tv3;
      cn = sigm(gf) * cs + sigm(gi) * tanh_(gg);
      hn = sigm(go) * tanh_(cn);
      cs = cn;
      hlast = (u32)f2bf(hn);
    }
    u32 h1 = (u32)__shfl_down((int)hlast, 1);
    u32 h2 = (u32)__shfl_down((int)hlast, 2);
    u32 h3 = (u32)__shfl_down((int)hlast, 3);
    u32 h4 = (u32)__shfl_down((int)hlast, 4);
    u32 h5 = (u32)__shfl_down((int)hlast, 5);
    u32 h6 = (u32)__shfl_down((int)hlast, 6);
    u32 h7 = (u32)__shfl_down((int)hlast, 7);
    if (packer) {
      i32x4 dv;
      dv[0] = (int)(((hlast & 0xFFFEu) | tgW) | (h1 << 16));
      dv[1] = (int)(((h2    & 0xFFFEu) | tgW) | (h3 << 16));
      dv[2] = (int)(((h4    & 0xFFFEu) | tgW) | (h5 << 16));
      dv[3] = (int)(((h6    & 0xFFFEu) | tgW) | (h7 << 16));
      store_x4_coh(bufW + (size_t)row_g * 2048 + (size_t)dim * 2, dv);
      // direct-stage own chunk (wg) for step t+1 into the other LDS buffer
      char* hd = (char*)hsW + r_act * 2048;
      *(i32x4*)(hd + ((64 * wg + 2 * d_act) ^ (r_act << 4))) = dv;
      asm volatile("s_waitcnt lgkmcnt(0)" ::: "memory");
      int old = atomicAdd(&cnt[(t + 1) & 1][wg], 1);
      if (old == 31) { rgen[wg] = t + 1; cnt[(t + 1) & 1][wg] = 0; }
    }

    // ---- plain output stores (overlap next step's polls) ----
    {
      float* po = &out_o[(size_t)row_g * (Tsz * Hsz) + (size_t)t * Hsz + dim];
      if (active) {
        *po = hn;
        if (t == Lr - 1) {
          out_hn[row_g * Hsz + dim] = hn;
          out_cn[row_g * Hsz + dim] = cn;
        }
      } else {
        *po = 0.f;             // inactive row inside live group
      }
    }
  }
}

// ---------- decode: dec[b,t,v] = out[b,t,:]@WdecT[:,v] + bdec[v] ----------
__global__ __launch_bounds__(256) void k_decode(const float* __restrict__ outp,
                                                const float* __restrict__ WdecT,
                                                const int* __restrict__ lens,
                                                const float* __restrict__ bdec,
                                                float* __restrict__ dec) {
  __shared__ float Al[64 * 132];
  __shared__ float Bl[64 * 112];
  const int tid = threadIdx.x;
  const int bid = blockIdx.x;          // 512
  const int b = bid >> 3;
  const int t0 = (bid & 7) * 128;
  const int L = lens[b];
  const int tx = tid & 15, ty = tid >> 4;
  float bd[7];
  #pragma unroll
  for (int n = 0; n < 7; ++n) { int v = tx + 16 * n; bd[n] = (v < Vsz) ? bdec[v] : 0.f; }

  if (t0 >= L) {       // whole block beyond length: decoded = bdec
    for (int m = ty; m < 128; m += 16) {
      size_t rowo = ((size_t)b * Tsz + t0 + m) * (size_t)Vsz;
      #pragma unroll
      for (int n = 0; n < 7; ++n) { int v = tx + 16 * n; if (v < Vsz) dec[rowo + v] = bd[n]; }
    }
    return;
  }

  float acc[8][7];
  #pragma unroll
  for (int j = 0; j < 8; ++j)
    #pragma unroll
    for (int n = 0; n < 7; ++n) acc[j][n] = 0.f;

  for (int kt = 0; kt < 16; ++kt) {
    int k0 = kt * 64;
    {   // stage A transposed: Al[k][m]
      int m = tid >> 1;
      int kh = (tid & 1) * 32;
      const float* src = outp + ((size_t)b * Tsz + t0 + m) * Hsz + k0 + kh;
      #pragma unroll
      for (int i = 0; i < 32; i += 4) {
        f32x4 v = *(const f32x4*)(src + i);
        Al[(kh + i + 0) * 132 + m] = v[0];
        Al[(kh + i + 1) * 132 + m] = v[1];
        Al[(kh + i + 2) * 132 + m] = v[2];
        Al[(kh + i + 3) * 132 + m] = v[3];
      }
    }
    {   // stage B
      const f32x4* s = (const f32x4*)(WdecT + (size_t)k0 * 112);
      f32x4* d4 = (f32x4*)Bl;
      for (int i = tid; i < 1792; i += 256) d4[i] = s[i];
    }
    __syncthreads();
    #pragma unroll 4
    for (int i = 0; i < 64; ++i) {
      float a[8], bv[7];
      #pragma unroll
      for (int j = 0; j < 8; ++j) a[j] = Al[i * 132 + ty + 16 * j];
      #pragma unroll
      for (int n = 0; n < 7; ++n) bv[n] = Bl[i * 112 + tx + 16 * n];
      #pragma unroll
      for (int j = 0; j < 8; ++j)
        #pragma unroll
        for (int n = 0; n < 7; ++n) acc[j][n] += a[j] * bv[n];
    }
    __syncthreads();
  }
  #pragma unroll
  for (int j = 0; j < 8; ++j) {
    int m = ty + 16 * j;
    size_t rowo = ((size_t)b * Tsz + t0 + m) * (size_t)Vsz;
    #pragma unroll
    for (int n = 0; n < 7; ++n) {
      int v = tx + 16 * n;
      if (v < Vsz) dec[rowo + v] = acc[j][n] + bd[n];
    }
  }
}

extern "C" void kernel_launch(void* const* d_in, const int* in_sizes, int n_in,
                              void* d_out, int out_size, void* d_ws, size_t ws_size,
                              hipStream_t stream) {
  const int*   chars = (const int*)d_in[0];
  const int*   lens  = (const int*)d_in[1];
  const float* emb   = (const float*)d_in[2];
  const float* Wih   = (const float*)d_in[3];
  const float* Whh   = (const float*)d_in[4];
  const float* bih   = (const float*)d_in[5];
  const float* bhh   = (const float*)d_in[6];
  const float* Wdec  = (const float*)d_in[7];
  const float* bdec  = (const float*)d_in[8];
  float* dout = (float*)d_out;
  char* ws = (char*)d_ws;
  float*          table = (float*)ws;                       // 1,638,400 B
  float*          WdecT = (float*)(ws + 1638400);           //   458,752 B
  unsigned short* hbf   = (unsigned short*)(ws + 2097152);  //   262,144 B
  int*            flags = (int*)(ws + 2359296);             //     2,048 B

  k_table<<<16, 256, 0, stream>>>(emb, Wih, bih, bhh, table);
  k_wdecT<<<448, 256, 0, stream>>>(Wdec, WdecT, flags);      // also zeroes flags
  k_zero_tail<<<64, 256, 0, stream>>>(lens, dout);
  k_lstm<<<256, 256, 0, stream>>>(chars, lens, Whh, table, hbf, flags, dout);
  k_decode<<<512, 256, 0, stream>>>(dout, WdecT, lens, bdec, dout + 67239936);
}

// Round 12
// 3373.286 us; speedup vs baseline: 4.5648x; 4.5648x over previous
//
#include <hip/hip_runtime.h>

#define Bsz 64
#define Tsz 1024
#define Vsz 100
#define Esz 100
#define Hsz 1024
#define G4  4096

typedef __attribute__((ext_vector_type(8))) short short8;
typedef __attribute__((ext_vector_type(4))) float f32x4;
typedef __attribute__((ext_vector_type(4))) int   i32x4;
typedef unsigned int u32;

// ---------- helpers ----------
__device__ __forceinline__ unsigned short f2bf(float f) {
  union { float f; u32 u; } v; v.f = f;
  u32 u = v.u + 0x7fffu + ((v.u >> 16) & 1u);   // RNE
  return (unsigned short)(u >> 16);
}
__device__ __forceinline__ float sigm(float x) { return 1.f / (1.f + __expf(-x)); }
__device__ __forceinline__ float tanh_(float x) {
  float e = __expf(2.f * x);
  return 1.f - 2.f / (e + 1.f);
}

// device-scope (LLC) coherent ops — proven rounds 2/3/7/8
__device__ __forceinline__ void store_s32_coh(int* p, int v) {
  asm volatile("global_store_dword %0, %1, off sc0 sc1" :: "v"(p), "v"(v) : "memory");
}
__device__ __forceinline__ int load_s32_coh(const int* p) {
  int v;
  asm volatile("global_load_dword %0, %1, off sc0 sc1\n\ts_waitcnt vmcnt(0)"
               : "=v"(v) : "v"(p) : "memory");
  return v;
}
__device__ __forceinline__ void store_x4_coh(void* p, i32x4 v) {
  asm volatile("global_store_dwordx4 %0, %1, off sc0 sc1" :: "v"(p), "v"(v) : "memory");
}
__device__ __forceinline__ void drain_vmem() {
  asm volatile("s_waitcnt vmcnt(0)" ::: "memory");
}
// issue-only coherent 16B load (wait separately with one vmcnt)
__device__ __forceinline__ void load_x4_coh_issue(i32x4* dst, const void* p) {
  asm volatile("global_load_dwordx4 %0, %1, off sc0 sc1"
               : "=v"(*dst) : "v"(p) : "memory");
}

// ---------- kernel A: gate lookup table  table[v][p] = emb[v]@Wih[orig(p)] + bih + bhh ----------
// permuted col p = wg*128 + g*32 + d  ->  orig = g*1024 + wg*32 + d   (wg 0..31, g 0..3, d 0..31)
__global__ __launch_bounds__(256) void k_table(const float* __restrict__ emb,
                                               const float* __restrict__ Wih,
                                               const float* __restrict__ bih,
                                               const float* __restrict__ bhh,
                                               float* __restrict__ table) {
  __shared__ float es[Vsz * Esz];
  int tid = threadIdx.x;
  for (int i = tid; i < Vsz * Esz; i += 256) es[i] = emb[i];
  __syncthreads();
  int p = blockIdx.x * 256 + tid;          // 0..4095
  int wg = p >> 7;
  int g = (p >> 5) & 3;
  int d = p & 31;
  int orig = g * Hsz + wg * 32 + d;
  float w[Esz];
  #pragma unroll
  for (int e = 0; e < Esz; ++e) w[e] = Wih[(size_t)orig * Esz + e];
  float bias = bih[orig] + bhh[orig];
  for (int v = 0; v < Vsz; ++v) {
    float acc = bias;
    #pragma unroll
    for (int e = 0; e < Esz; ++e) acc += es[v * Esz + e] * w[e];
    table[(size_t)v * G4 + p] = acc;
  }
}

// ---------- kernel W: WdecT[k][v] (pad v to 112) + zero sync flags ----------
__global__ __launch_bounds__(256) void k_wdecT(const float* __restrict__ Wdec,
                                               float* __restrict__ WdecT,
                                               int* __restrict__ flags) {  // 512 ints
  if (blockIdx.x == 0) {
    for (int i = threadIdx.x; i < 512; i += 256) store_s32_coh(flags + i, 0);
  }
  int idx = blockIdx.x * 256 + threadIdx.x;   // k*112+v
  if (idx >= 1024 * 112) return;
  int k = idx / 112, v = idx - k * 112;
  WdecT[idx] = (v < Vsz) ? Wdec[(size_t)v * Hsz + k] : 0.f;
}

// ---------- zero tail: out rows with t >= OWN length (per-row, not per-group) ----------
__global__ __launch_bounds__(256) void k_zero_tail(const int* __restrict__ lens,
                                                   float* __restrict__ out_o) {
  int b = blockIdx.x;                       // 0..63
  int L = lens[b];
  f32x4 z = {0.f, 0.f, 0.f, 0.f};
  for (int t = L; t < Tsz; ++t) {
    f32x4* p = (f32x4*)(out_o + ((size_t)b * Tsz + t) * Hsz);
    p[threadIdx.x] = z;                     // 256 x 4 floats = 1024
  }
}

// ---------- persistent LSTM, tag-in-data seqlock (round-8 core + decay polling) ----------
// 256 WGs x 256 thr, plain launch. 8 groups (bid&7) of 32 WGs; group owns batch rows
// grp*8..+7; WG rank wg=bid>>3 owns dims wg*32..+31 (all 4 gates, B in regs).
// h handoff: double-buffered [2][64][1024] bf16, tag bit in every dword LSB (= (t>>1)&1).
// Producers: tagged sc0sc1 dwordx4 stores, ONLY while the row is active (frozen rows stop;
// consumers reuse byte-identical stale LDS). Consumers: per-piece pending flags — each
// retry round re-loads only still-stale 16B pieces and ds_writes them as they land
// (poll IS the staging load; traffic decays; no added serial stages).
// All polls budget-bounded: failure -> visible absmax error, never a hang.
__global__ __launch_bounds__(256, 1) void k_lstm(const int* __restrict__ chars,
                                                 const int* __restrict__ lens,
                                                 const float* __restrict__ Whh,
                                                 const float* __restrict__ table,
                                                 unsigned short* __restrict__ hbf, // [2][64][1024]
                                                 int* __restrict__ flags,          // [8][64] (32 used)
                                                 float* __restrict__ dout) {
  const int tid = threadIdx.x;
  const int lane = tid & 63;
  const int wave = tid >> 6;                 // 0..3 (= gate index for MFMA tiles)
  const int bid = blockIdx.x;
  const int grp = bid & 7;                   // group
  const int wg  = bid >> 3;                  // 0..31 rank in group
  const int wgdim0 = wg * 32;

  float* out_o  = dout;
  float* out_hn = dout + 67108864;
  float* out_cn = dout + 67174400;

  int* gflags = flags + grp * 64;            // 32 packed flags (128B)
  int* myflag = gflags + wg;

  __shared__ unsigned short hstage[16 * 1024];   // 32KB; rows 0-7 staged, 8-15 zero
  __shared__ float gatex[4][8][33];              // [gate][row][dim] 4.2KB

  // ---- roles ----
  const int r_act = tid >> 5;                // act/staging row 0..7
  const int d_act = tid & 31;                // dim within WG slice
  const int l31 = tid & 31;
  const int row_g = grp * 8 + r_act;
  const int Lr = lens[row_g];
  const int Lmax = lens[grp * 8];            // sorted descending -> group max
  const int dim = wgdim0 + d_act;
  const int packer = ((d_act & 7) == 0);
  float cs = 0.f;
  u32 hlast = 0;                             // bf16 bits of h(t) for (row_g, dim)
  int budget = 1 << 20;                      // cumulative poll rounds (anti-hang)

  // ---- init: tag both buffers (own slice), replay-safe ----
  // buf0 = h(0)=0 tag 0; buf1 = stale vs first read (tag 1).
  if (packer) {
    char* c0 = (char*)hbf + (size_t)row_g * 2048 + (size_t)dim * 2;
    i32x4 z0 = {0, 0, 0, 0};
    i32x4 z1 = {0x00010001, 0x00010001, 0x00010001, 0x00010001};
    store_x4_coh(c0, z0);
    store_x4_coh(c0 + 131072, z1);
  }
  drain_vmem();
  __syncthreads();
  if (tid == 0) store_s32_coh(myflag, 1);

  // ---- one-time heavy work (overlaps other WGs' init) ----
  short8 Bf[32][2];
  {
    const int col = lane & 15;
    const int ko = (lane >> 4) * 8;
    #pragma unroll
    for (int kk = 0; kk < 32; ++kk) {
      #pragma unroll
      for (int hh = 0; hh < 2; ++hh) {
        int orig = wave * Hsz + wgdim0 + hh * 16 + col;
        const float* src = Whh + (size_t)orig * Hsz + kk * 32 + ko;
        f32x4 f0 = *(const f32x4*)(src);
        f32x4 f1 = *(const f32x4*)(src + 4);
        short8 bb;
        bb[0] = (short)f2bf(f0[0]); bb[1] = (short)f2bf(f0[1]);
        bb[2] = (short)f2bf(f0[2]); bb[3] = (short)f2bf(f0[3]);
        bb[4] = (short)f2bf(f1[0]); bb[5] = (short)f2bf(f1[1]);
        bb[6] = (short)f2bf(f1[2]); bb[7] = (short)f2bf(f1[3]);
        Bf[kk][hh] = bb;
      }
    }
  }
  {   // zero hstage rows 8..15 once (MFMA upper rows stay zero)
    f32x4 z = {0.f, 0.f, 0.f, 0.f};
    f32x4* hz = (f32x4*)(hstage + 8 * 1024);
    for (int i = tid; i < 1024; i += 256) hz[i] = z;
  }

  // ---- init barrier (device scope, bounded) ----
  if (wave == 0) {
    const int* fp = gflags + (lane & 31);
    for (;;) {
      int f = load_s32_coh(fp);
      if (__all(f >= 1)) break;
      if (--budget < 0) break;
    }
  }
  __syncthreads();

  for (int t = 0; t < Tsz; ++t) {
    if (Lmax <= t) break;                    // uniform across group
    const u32 tgR = (u32)((t >> 1) & 1);           // expected tag of h(t) in buf t&1
    const u32 tgW = (u32)(((t + 1) >> 1) & 1);     // tag for h(t+1) in buf (t+1)&1
    const char* bufR = (const char*)hbf + (size_t)(t & 1) * 131072;
    char* bufW = (char*)hbf + (size_t)((t & 1) ^ 1) * 131072;

    const int active = (Lr > t);
    int ch = active ? chars[(size_t)row_g * Tsz + t] : 0;

    // ---- gate-table gather (plain cached; hides under the poll) ----
    float tv0 = 0.f, tv1 = 0.f, tv2 = 0.f, tv3 = 0.f;
    if (active) {
      const float* tb = table + (size_t)ch * G4 + wg * 128 + d_act;
      tv0 = tb[0]; tv1 = tb[32]; tv2 = tb[64]; tv3 = tb[96];
    }

    // ---- poll+stage with per-piece decay; frozen rows (Lr < t) skipped entirely ----
    // (h(t) was stored at step t-1 iff Lr > t-1, i.e. Lr >= t; t=0 comes from init)
    if (Lr >= t) {
      const char* q = bufR + (size_t)row_g * 2048 + 16 * l31;
      char* hsb = (char*)hstage + r_act * 2048;
      const int swz = r_act << 4;
      const int y = 16 * l31;
      i32x4 c0, c1, c2, c3;
      bool n0 = true, n1 = true, n2 = true, n3 = true;
      for (;;) {
        if (n0) load_x4_coh_issue(&c0, q);
        if (n1) load_x4_coh_issue(&c1, q + 512);
        if (n2) load_x4_coh_issue(&c2, q + 1024);
        if (n3) load_x4_coh_issue(&c3, q + 1536);
        drain_vmem();
        if (n0) {
          u32 orb = (u32)(c0[0] | c0[1] | c0[2] | c0[3]);
          u32 anb = (u32)(c0[0] & c0[1] & c0[2] & c0[3]);
          if (!(tgR ? ((anb & 1u) ^ 1u) : (orb & 1u))) {
            *(i32x4*)(hsb + ((y) ^ swz)) = c0;  n0 = false;
          }
        }
        if (n1) {
          u32 orb = (u32)(c1[0] | c1[1] | c1[2] | c1[3]);
          u32 anb = (u32)(c1[0] & c1[1] & c1[2] & c1[3]);
          if (!(tgR ? ((anb & 1u) ^ 1u) : (orb & 1u))) {
            *(i32x4*)(hsb + ((y + 512) ^ swz)) = c1;  n1 = false;
          }
        }
        if (n2) {
          u32 orb = (u32)(c2[0] | c2[1] | c2[2] | c2[3]);
          u32 anb = (u32)(c2[0] & c2[1] & c2[2] & c2[3]);
          if (!(tgR ? ((anb & 1u) ^ 1u) : (orb & 1u))) {
            *(i32x4*)(hsb + ((y + 1024) ^ swz)) = c2;  n2 = false;
          }
        }
        if (n3) {
          u32 orb = (u32)(c3[0] | c3[1] | c3[2] | c3[3]);
          u32 anb = (u32)(c3[0] & c3[1] & c3[2] & c3[3]);
          if (!(tgR ? ((anb & 1u) ^ 1u) : (orb & 1u))) {
            *(i32x4*)(hsb + ((y + 1536) ^ swz)) = c3;  n3 = false;
          }
        }
        if (!(n0 | n1 | n2 | n3)) break;
        if (--budget < 0) break;
      }
    }
    __syncthreads();

    // ---- MFMA: 16(8 used) rows x 32 dims x K=1024; B in regs; parity accumulators ----
    f32x4 a00 = {0.f,0.f,0.f,0.f}, a01 = {0.f,0.f,0.f,0.f};
    f32x4 a10 = {0.f,0.f,0.f,0.f}, a11 = {0.f,0.f,0.f,0.f};
    {
      const int arow = lane & 15;
      const int aswz = (arow & 7) << 4;
      const int axb = (lane >> 4) << 4;
      const char* hsb = (const char*)hstage;
      #pragma unroll
      for (int kk = 0; kk < 32; ++kk) {
        int off = ((kk << 6) | axb) ^ aswz;
        short8 av = *(const short8*)(hsb + arow * 2048 + off);
        if ((kk & 1) == 0) {
          a00 = __builtin_amdgcn_mfma_f32_16x16x32_bf16(av, Bf[kk][0], a00, 0, 0, 0);
          a10 = __builtin_amdgcn_mfma_f32_16x16x32_bf16(av, Bf[kk][1], a10, 0, 0, 0);
        } else {
          a01 = __builtin_amdgcn_mfma_f32_16x16x32_bf16(av, Bf[kk][0], a01, 0, 0, 0);
          a11 = __builtin_amdgcn_mfma_f32_16x16x32_bf16(av, Bf[kk][1], a11, 0, 0, 0);
        }
      }
    }
    if (lane < 32) {           // rows 0..7 only
      f32x4 v0 = a00 + a01;    // dims 0..15
      f32x4 v1 = a10 + a11;    // dims 16..31
      int col = lane & 15;
      int r0 = (lane >> 4) * 4;
      #pragma unroll
      for (int i = 0; i < 4; ++i) {
        gatex[wave][r0 + i][col]      = v0[i];
        gatex[wave][r0 + i][16 + col] = v1[i];
      }
    }
    __syncthreads();

    // ---- activation + state; release = tagged store (active rows only) ----
    float hn = 0.f, cn = 0.f;
    if (active) {
      float gi = gatex[0][r_act][d_act] + tv0;
      float gf = gatex[1][r_act][d_act] + tv1;
      float gg = gatex[2][r_act][d_act] + tv2;
      float go = gatex[3][r_act][d_act] + tv3;
      cn = sigm(gf) * cs + sigm(gi) * tanh_(gg);
      hn = sigm(go) * tanh_(cn);
      cs = cn;
      hlast = (u32)f2bf(hn);
    }
    // pack 8 consecutive dims via wave-local shuffles (packer lane ≡ 0 mod 8)
    u32 h1 = (u32)__shfl_down((int)hlast, 1);
    u32 h2 = (u32)__shfl_down((int)hlast, 2);
    u32 h3 = (u32)__shfl_down((int)hlast, 3);
    u32 h4 = (u32)__shfl_down((int)hlast, 4);
    u32 h5 = (u32)__shfl_down((int)hlast, 5);
    u32 h6 = (u32)__shfl_down((int)hlast, 6);
    u32 h7 = (u32)__shfl_down((int)hlast, 7);
    if (packer && active) {                  // frozen rows stop storing (consumers skip them)
      i32x4 dv;
      dv[0] = (int)(((hlast & 0xFFFEu) | tgW) | (h1 << 16));
      dv[1] = (int)(((h2    & 0xFFFEu) | tgW) | (h3 << 16));
      dv[2] = (int)(((h4    & 0xFFFEu) | tgW) | (h5 << 16));
      dv[3] = (int)(((h6    & 0xFFFEu) | tgW) | (h7 << 16));
      store_x4_coh(bufW + (size_t)row_g * 2048 + (size_t)dim * 2, dv);
    }

    // ---- plain output stores (overlap next poll); tails handled by k_zero_tail ----
    if (active) {
      out_o[(size_t)row_g * (Tsz * Hsz) + (size_t)t * Hsz + dim] = hn;
      if (t == Lr - 1) {
        out_hn[row_g * Hsz + dim] = hn;
        out_cn[row_g * Hsz + dim] = cn;
      }
    }
  }
}

// ---------- decode: dec[b,t,v] = out[b,t,:]@WdecT[:,v] + bdec[v] ----------
__global__ __launch_bounds__(256) void k_decode(const float* __restrict__ outp,
                                                const float* __restrict__ WdecT,
                                                const int* __restrict__ lens,
                                                const float* __restrict__ bdec,
                                                float* __restrict__ dec) {
  __shared__ float Al[64 * 132];
  __shared__ float Bl[64 * 112];
  const int tid = threadIdx.x;
  const int bid = blockIdx.x;          // 512
  const int b = bid >> 3;
  const int t0 = (bid & 7) * 128;
  const int L = lens[b];
  const int tx = tid & 15, ty = tid >> 4;
  float bd[7];
  #pragma unroll
  for (int n = 0; n < 7; ++n) { int v = tx + 16 * n; bd[n] = (v < Vsz) ? bdec[v] : 0.f; }

  if (t0 >= L) {       // whole block beyond length: decoded = bdec
    for (int m = ty; m < 128; m += 16) {
      size_t rowo = ((size_t)b * Tsz + t0 + m) * (size_t)Vsz;
      #pragma unroll
      for (int n = 0; n < 7; ++n) { int v = tx + 16 * n; if (v < Vsz) dec[rowo + v] = bd[n]; }
    }
    return;
  }

  float acc[8][7];
  #pragma unroll
  for (int j = 0; j < 8; ++j)
    #pragma unroll
    for (int n = 0; n < 7; ++n) acc[j][n] = 0.f;

  for (int kt = 0; kt < 16; ++kt) {
    int k0 = kt * 64;
    {   // stage A transposed: Al[k][m]
      int m = tid >> 1;
      int kh = (tid & 1) * 32;
      const float* src = outp + ((size_t)b * Tsz + t0 + m) * Hsz + k0 + kh;
      #pragma unroll
      for (int i = 0; i < 32; i += 4) {
        f32x4 v = *(const f32x4*)(src + i);
        Al[(kh + i + 0) * 132 + m] = v[0];
        Al[(kh + i + 1) * 132 + m] = v[1];
        Al[(kh + i + 2) * 132 + m] = v[2];
        Al[(kh + i + 3) * 132 + m] = v[3];
      }
    }
    {   // stage B
      const f32x4* s = (const f32x4*)(WdecT + (size_t)k0 * 112);
      f32x4* d4 = (f32x4*)Bl;
      for (int i = tid; i < 1792; i += 256) d4[i] = s[i];
    }
    __syncthreads();
    #pragma unroll 4
    for (int i = 0; i < 64; ++i) {
      float a[8], bv[7];
      #pragma unroll
      for (int j = 0; j < 8; ++j) a[j] = Al[i * 132 + ty + 16 * j];
      #pragma unroll
      for (int n = 0; n < 7; ++n) bv[n] = Bl[i * 112 + tx + 16 * n];
      #pragma unroll
      for (int j = 0; j < 8; ++j)
        #pragma unroll
        for (int n = 0; n < 7; ++n) acc[j][n] += a[j] * bv[n];
    }
    __syncthreads();
  }
  #pragma unroll
  for (int j = 0; j < 8; ++j) {
    int m = ty + 16 * j;
    size_t rowo = ((size_t)b * Tsz + t0 + m) * (size_t)Vsz;
    #pragma unroll
    for (int n = 0; n < 7; ++n) {
      int v = tx + 16 * n;
      if (v < Vsz) dec[rowo + v] = acc[j][n] + bd[n];
    }
  }
}

extern "C" void kernel_launch(void* const* d_in, const int* in_sizes, int n_in,
                              void* d_out, int out_size, void* d_ws, size_t ws_size,
                              hipStream_t stream) {
  const int*   chars = (const int*)d_in[0];
  const int*   lens  = (const int*)d_in[1];
  const float* emb   = (const float*)d_in[2];
  const float* Wih   = (const float*)d_in[3];
  const float* Whh   = (const float*)d_in[4];
  const float* bih   = (const float*)d_in[5];
  const float* bhh   = (const float*)d_in[6];
  const float* Wdec  = (const float*)d_in[7];
  const float* bdec  = (const float*)d_in[8];
  float* dout = (float*)d_out;
  char* ws = (char*)d_ws;
  float*          table = (float*)ws;                       // 1,638,400 B
  float*          WdecT = (float*)(ws + 1638400);           //   458,752 B
  unsigned short* hbf   = (unsigned short*)(ws + 2097152);  //   262,144 B
  int*            flags = (int*)(ws + 2359296);             //     2,048 B

  k_table<<<16, 256, 0, stream>>>(emb, Wih, bih, bhh, table);
  k_wdecT<<<448, 256, 0, stream>>>(Wdec, WdecT, flags);      // also zeroes flags
  k_zero_tail<<<64, 256, 0, stream>>>(lens, dout);
  k_lstm<<<256, 256, 0, stream>>>(chars, lens, Whh, table, hbf, flags, dout);
  k_decode<<<512, 256, 0, stream>>>(dout, WdecT, lens, bdec, dout + 67239936);
}

// Round 13
// 2925.235 us; speedup vs baseline: 5.2640x; 1.1532x over previous
//
#include <hip/hip_runtime.h>

#define Bsz 64
#define Tsz 1024
#define Vsz 100
#define Esz 100
#define Hsz 1024
#define G4  4096

typedef __attribute__((ext_vector_type(8))) short short8;
typedef __attribute__((ext_vector_type(4))) float f32x4;
typedef __attribute__((ext_vector_type(4))) int   i32x4;
typedef unsigned int u32;

// ---------- helpers ----------
__device__ __forceinline__ unsigned short f2bf(float f) {
  union { float f; u32 u; } v; v.f = f;
  u32 u = v.u + 0x7fffu + ((v.u >> 16) & 1u);   // RNE
  return (unsigned short)(u >> 16);
}
__device__ __forceinline__ float sigm(float x) { return 1.f / (1.f + __expf(-x)); }
__device__ __forceinline__ float tanh_(float x) {
  float e = __expf(2.f * x);
  return 1.f - 2.f / (e + 1.f);
}

// device-scope (LLC) coherent ops — proven rounds 2/3/7/8
__device__ __forceinline__ void store_s32_coh(int* p, int v) {
  asm volatile("global_store_dword %0, %1, off sc0 sc1" :: "v"(p), "v"(v) : "memory");
}
__device__ __forceinline__ int load_s32_coh(const int* p) {
  int v;
  asm volatile("global_load_dword %0, %1, off sc0 sc1\n\ts_waitcnt vmcnt(0)"
               : "=v"(v) : "v"(p) : "memory");
  return v;
}
__device__ __forceinline__ void store_x4_coh(void* p, i32x4 v) {
  asm volatile("global_store_dwordx4 %0, %1, off sc0 sc1" :: "v"(p), "v"(v) : "memory");
}
__device__ __forceinline__ void drain_vmem() {
  asm volatile("s_waitcnt vmcnt(0)" ::: "memory");
}

// ---------- kernel A: gate lookup table  table[v][p] = emb[v]@Wih[orig(p)] + bih + bhh ----------
// permuted col p = wg*128 + g*32 + d  ->  orig = g*1024 + wg*32 + d   (wg 0..31, g 0..3, d 0..31)
__global__ __launch_bounds__(256) void k_table(const float* __restrict__ emb,
                                               const float* __restrict__ Wih,
                                               const float* __restrict__ bih,
                                               const float* __restrict__ bhh,
                                               float* __restrict__ table) {
  __shared__ float es[Vsz * Esz];
  int tid = threadIdx.x;
  for (int i = tid; i < Vsz * Esz; i += 256) es[i] = emb[i];
  __syncthreads();
  int p = blockIdx.x * 256 + tid;          // 0..4095
  int wg = p >> 7;
  int g = (p >> 5) & 3;
  int d = p & 31;
  int orig = g * Hsz + wg * 32 + d;
  float w[Esz];
  #pragma unroll
  for (int e = 0; e < Esz; ++e) w[e] = Wih[(size_t)orig * Esz + e];
  float bias = bih[orig] + bhh[orig];
  for (int v = 0; v < Vsz; ++v) {
    float acc = bias;
    #pragma unroll
    for (int e = 0; e < Esz; ++e) acc += es[v * Esz + e] * w[e];
    table[(size_t)v * G4 + p] = acc;
  }
}

// ---------- kernel W: WdecT[k][v] (pad v to 112) + zero sync flags ----------
__global__ __launch_bounds__(256) void k_wdecT(const float* __restrict__ Wdec,
                                               float* __restrict__ WdecT,
                                               int* __restrict__ flags) {  // 512 ints
  if (blockIdx.x == 0) {
    for (int i = threadIdx.x; i < 512; i += 256) store_s32_coh(flags + i, 0);
  }
  int idx = blockIdx.x * 256 + threadIdx.x;   // k*112+v
  if (idx >= 1024 * 112) return;
  int k = idx / 112, v = idx - k * 112;
  WdecT[idx] = (v < Vsz) ? Wdec[(size_t)v * Hsz + k] : 0.f;
}

// ---------- zero tail: out rows with t >= group Lmax ----------
__global__ __launch_bounds__(256) void k_zero_tail(const int* __restrict__ lens,
                                                   float* __restrict__ out_o) {
  int b = blockIdx.x;                       // 0..63
  int Lmax = lens[(b >> 3) << 3];
  f32x4 z = {0.f, 0.f, 0.f, 0.f};
  for (int t = Lmax; t < Tsz; ++t) {
    f32x4* p = (f32x4*)(out_o + ((size_t)b * Tsz + t) * Hsz);
    p[threadIdx.x] = z;                     // 256 x 4 floats = 1024
  }
}

// ---------- persistent LSTM, tag-in-data seqlock handoff (round-8 core, best measured) ----------
// 256 WGs x 256 thr, plain launch. 8 groups (bid&7) of 32 WGs; group owns batch rows
// grp*8..+7; WG rank wg=bid>>3 owns dims wg*32..+31 (all 4 gates, B in regs).
// h handoff: double-buffered [2][64][1024] bf16, LINEAR layout. Tag bit = LSB of the low
// bf16 of EVERY dword = (t>>1)&1 for data of step t in buffer t&1 (stale = t-2 = opposite
// tag; dword-granular tags make torn 16B stores harmless). Producers: tagged sc0sc1
// dwordx4 stores (the store IS the release — no drain/flag/ack). Consumers: poll the data
// itself with sc0sc1 dwordx4 loads until tags match, then ds_write (XOR-swizzled) to LDS.
// Device-scope flag barrier only in one-time init (also re-tags both buffers: replay-safe).
// All polls budget-bounded: failure -> visible absmax error, never a hang.
__global__ __launch_bounds__(256, 1) void k_lstm(const int* __restrict__ chars,
                                                 const int* __restrict__ lens,
                                                 const float* __restrict__ Whh,
                                                 const float* __restrict__ table,
                                                 unsigned short* __restrict__ hbf, // [2][64][1024]
                                                 int* __restrict__ flags,          // [8][64] (32 used)
                                                 float* __restrict__ dout) {
  const int tid = threadIdx.x;
  const int lane = tid & 63;
  const int wave = tid >> 6;                 // 0..3 (= gate index for MFMA tiles)
  const int bid = blockIdx.x;
  const int grp = bid & 7;                   // group
  const int wg  = bid >> 3;                  // 0..31 rank in group
  const int wgdim0 = wg * 32;

  float* out_o  = dout;
  float* out_hn = dout + 67108864;
  float* out_cn = dout + 67174400;

  int* gflags = flags + grp * 64;            // 32 packed flags (128B)
  int* myflag = gflags + wg;

  __shared__ unsigned short hstage[16 * 1024];   // 32KB; rows 0-7 staged, 8-15 zero
  __shared__ float gatex[4][8][33];              // [gate][row][dim] 4.2KB

  // ---- roles ----
  const int r_act = tid >> 5;                // producer/consumer row 0..7
  const int d_act = tid & 31;                // dim within WG slice
  const int l31 = tid & 31;
  const int row_g = grp * 8 + r_act;
  const int Lr = lens[row_g];
  const int Lmax = lens[grp * 8];            // sorted descending -> group max
  const int dim = wgdim0 + d_act;
  const int packer = ((d_act & 7) == 0);
  float cs = 0.f;
  u32 hlast = 0;                             // bf16 bits of h(t) for (row_g, dim)
  int budget = 1 << 20;                      // cumulative poll rounds (anti-hang)

  // ---- init: tag both buffers (own slice), replay-safe ----
  // buf0 = h(0)=0, tag T(0)=0 (0x00000000); buf1 = stale vs T(1)=0 (tag bit 1).
  if (packer) {
    char* c0 = (char*)hbf + (size_t)row_g * 2048 + (size_t)(dim) * 2;
    i32x4 z0 = {0, 0, 0, 0};
    i32x4 z1 = {0x00010001, 0x00010001, 0x00010001, 0x00010001};
    store_x4_coh(c0, z0);
    store_x4_coh(c0 + 131072, z1);
  }
  drain_vmem();
  __syncthreads();
  if (tid == 0) store_s32_coh(myflag, 1);

  // ---- one-time heavy work (overlaps other WGs' init) ----
  short8 Bf[32][2];
  {
    const int col = lane & 15;
    const int ko = (lane >> 4) * 8;
    #pragma unroll
    for (int kk = 0; kk < 32; ++kk) {
      #pragma unroll
      for (int hh = 0; hh < 2; ++hh) {
        int orig = wave * Hsz + wgdim0 + hh * 16 + col;
        const float* src = Whh + (size_t)orig * Hsz + kk * 32 + ko;
        f32x4 f0 = *(const f32x4*)(src);
        f32x4 f1 = *(const f32x4*)(src + 4);
        short8 bb;
        bb[0] = (short)f2bf(f0[0]); bb[1] = (short)f2bf(f0[1]);
        bb[2] = (short)f2bf(f0[2]); bb[3] = (short)f2bf(f0[3]);
        bb[4] = (short)f2bf(f1[0]); bb[5] = (short)f2bf(f1[1]);
        bb[6] = (short)f2bf(f1[2]); bb[7] = (short)f2bf(f1[3]);
        Bf[kk][hh] = bb;
      }
    }
  }
  {   // zero hstage rows 8..15 once (MFMA upper rows stay zero)
    f32x4 z = {0.f, 0.f, 0.f, 0.f};
    f32x4* hz = (f32x4*)(hstage + 8 * 1024);
    for (int i = tid; i < 1024; i += 256) hz[i] = z;
  }

  // ---- init barrier (device scope, bounded) ----
  if (wave == 0) {
    const int* fp = gflags + (lane & 31);
    for (;;) {
      int f = load_s32_coh(fp);
      if (__all(f >= 1)) break;
      if (--budget < 0) break;
    }
  }
  __syncthreads();

  for (int t = 0; t < Tsz; ++t) {
    if (Lmax <= t) break;                    // uniform across group
    const u32 tgR = (u32)((t >> 1) & 1);           // expected tag of h(t) in buf t&1
    const u32 tgW = (u32)(((t + 1) >> 1) & 1);     // tag for h(t+1) in buf (t+1)&1
    const char* bufR = (const char*)hbf + (size_t)(t & 1) * 131072;
    char* bufW = (char*)hbf + (size_t)((t & 1) ^ 1) * 131072;

    const int active = (Lr > t);
    int ch = active ? chars[(size_t)row_g * Tsz + t] : 0;

    // ---- gate-table gather (plain cached; hides under the poll) ----
    float tv0 = 0.f, tv1 = 0.f, tv2 = 0.f, tv3 = 0.f;
    if (active) {
      const float* tb = table + (size_t)ch * G4 + wg * 128 + d_act;
      tv0 = tb[0]; tv1 = tb[32]; tv2 = tb[64]; tv3 = tb[96];
    }

    // ---- poll+stage: 4 chunks of row (grp*8 + r_act), bytes 16*l31 + 512*i ----
    {
      const char* q = bufR + (size_t)row_g * 2048 + 16 * l31;
      i32x4 c0, c1, c2, c3;
      for (;;) {
        asm volatile(
          "global_load_dwordx4 %0, %4, off sc0 sc1\n\t"
          "global_load_dwordx4 %1, %5, off sc0 sc1\n\t"
          "global_load_dwordx4 %2, %6, off sc0 sc1\n\t"
          "global_load_dwordx4 %3, %7, off sc0 sc1\n\t"
          "s_waitcnt vmcnt(0)"
          : "=v"(c0), "=v"(c1), "=v"(c2), "=v"(c3)
          : "v"(q), "v"(q + 512), "v"(q + 1024), "v"(q + 1536)
          : "memory");
        u32 acc = (u32)(c0[0] | c0[1] | c0[2] | c0[3]) ;
        u32 ac2 = (u32)(c1[0] | c1[1] | c1[2] | c1[3]);
        u32 ac3 = (u32)(c2[0] | c2[1] | c2[2] | c2[3]);
        u32 ac4 = (u32)(c3[0] | c3[1] | c3[2] | c3[3]);
        u32 anb = (u32)(c0[0] & c0[1] & c0[2] & c0[3] &
                        c1[0] & c1[1] & c1[2] & c1[3] &
                        c2[0] & c2[1] & c2[2] & c2[3] &
                        c3[0] & c3[1] & c3[2] & c3[3]);
        u32 orb = acc | ac2 | ac3 | ac4;
        // ready: all 16 dword LSBs == tgR  <=>  (tgR ? and==1 : or==0)
        u32 bad = tgR ? ((anb & 1u) ^ 1u) : (orb & 1u);
        if (!bad) break;
        if (--budget < 0) break;
      }
      // ds_write with both-sides XOR swizzle (rule #21): linear global, swizzled LDS
      char* hsb = (char*)hstage + r_act * 2048;
      const int swz = r_act << 4;
      const int y = 16 * l31;
      *(i32x4*)(hsb + ((y)        ^ swz)) = c0;
      *(i32x4*)(hsb + ((y + 512)  ^ swz)) = c1;
      *(i32x4*)(hsb + ((y + 1024) ^ swz)) = c2;
      *(i32x4*)(hsb + ((y + 1536) ^ swz)) = c3;
    }
    __syncthreads();

    // ---- MFMA: 16(8 used) rows x 32 dims x K=1024; B in regs; parity accumulators ----
    f32x4 a00 = {0.f,0.f,0.f,0.f}, a01 = {0.f,0.f,0.f,0.f};
    f32x4 a10 = {0.f,0.f,0.f,0.f}, a11 = {0.f,0.f,0.f,0.f};
    {
      const int arow = lane & 15;
      const int aswz = (arow & 7) << 4;
      const int axb = (lane >> 4) << 4;
      const char* hsb = (const char*)hstage;
      #pragma unroll
      for (int kk = 0; kk < 32; ++kk) {
        int off = ((kk << 6) | axb) ^ aswz;
        short8 av = *(const short8*)(hsb + arow * 2048 + off);
        if ((kk & 1) == 0) {
          a00 = __builtin_amdgcn_mfma_f32_16x16x32_bf16(av, Bf[kk][0], a00, 0, 0, 0);
          a10 = __builtin_amdgcn_mfma_f32_16x16x32_bf16(av, Bf[kk][1], a10, 0, 0, 0);
        } else {
          a01 = __builtin_amdgcn_mfma_f32_16x16x32_bf16(av, Bf[kk][0], a01, 0, 0, 0);
          a11 = __builtin_amdgcn_mfma_f32_16x16x32_bf16(av, Bf[kk][1], a11, 0, 0, 0);
        }
      }
    }
    if (lane < 32) {           // rows 0..7 only
      f32x4 v0 = a00 + a01;    // dims 0..15
      f32x4 v1 = a10 + a11;    // dims 16..31
      int col = lane & 15;
      int r0 = (lane >> 4) * 4;
      #pragma unroll
      for (int i = 0; i < 4; ++i) {
        gatex[wave][r0 + i][col]      = v0[i];
        gatex[wave][r0 + i][16 + col] = v1[i];
      }
    }
    __syncthreads();

    // ---- activation + state; release = tagged store (no drain/flag) ----
    float hn = 0.f, cn = 0.f;
    if (active) {
      float gi = gatex[0][r_act][d_act] + tv0;
      float gf = gatex[1][r_act][d_act] + tv1;
      float gg = gatex[2][r_act][d_act] + tv2;
      float go = gatex[3][r_act][d_act] + tv3;
      cn = sigm(gf) * cs + sigm(gi) * tanh_(gg);
      hn = sigm(go) * tanh_(cn);
      cs = cn;
      hlast = (u32)f2bf(hn);
    }
    // pack 8 consecutive dims via wave-local shuffles (packer lane ≡ 0 mod 8)
    u32 h1 = (u32)__shfl_down((int)hlast, 1);
    u32 h2 = (u32)__shfl_down((int)hlast, 2);
    u32 h3 = (u32)__shfl_down((int)hlast, 3);
    u32 h4 = (u32)__shfl_down((int)hlast, 4);
    u32 h5 = (u32)__shfl_down((int)hlast, 5);
    u32 h6 = (u32)__shfl_down((int)hlast, 6);
    u32 h7 = (u32)__shfl_down((int)hlast, 7);
    if (packer) {
      i32x4 dv;
      dv[0] = (int)(((hlast & 0xFFFEu) | tgW) | (h1 << 16));
      dv[1] = (int)(((h2    & 0xFFFEu) | tgW) | (h3 << 16));
      dv[2] = (int)(((h4    & 0xFFFEu) | tgW) | (h5 << 16));
      dv[3] = (int)(((h6    & 0xFFFEu) | tgW) | (h7 << 16));
      store_x4_coh(bufW + (size_t)row_g * 2048 + (size_t)dim * 2, dv);
    }

    // ---- plain output stores (overlap next poll) ----
    {
      float* po = &out_o[(size_t)row_g * (Tsz * Hsz) + (size_t)t * Hsz + dim];
      if (active) {
        *po = hn;
        if (t == Lr - 1) {
          out_hn[row_g * Hsz + dim] = hn;
          out_cn[row_g * Hsz + dim] = cn;
        }
      } else {
        *po = 0.f;             // inactive row inside live group
      }
    }
  }
}

// ---------- decode: dec[b,t,v] = out[b,t,:]@WdecT[:,v] + bdec[v] ----------
__global__ __launch_bounds__(256) void k_decode(const float* __restrict__ outp,
                                                const float* __restrict__ WdecT,
                                                const int* __restrict__ lens,
                                                const float* __restrict__ bdec,
                                                float* __restrict__ dec) {
  __shared__ float Al[64 * 132];
  __shared__ float Bl[64 * 112];
  const int tid = threadIdx.x;
  const int bid = blockIdx.x;          // 512
  const int b = bid >> 3;
  const int t0 = (bid & 7) * 128;
  const int L = lens[b];
  const int tx = tid & 15, ty = tid >> 4;
  float bd[7];
  #pragma unroll
  for (int n = 0; n < 7; ++n) { int v = tx + 16 * n; bd[n] = (v < Vsz) ? bdec[v] : 0.f; }

  if (t0 >= L) {       // whole block beyond length: decoded = bdec
    for (int m = ty; m < 128; m += 16) {
      size_t rowo = ((size_t)b * Tsz + t0 + m) * (size_t)Vsz;
      #pragma unroll
      for (int n = 0; n < 7; ++n) { int v = tx + 16 * n; if (v < Vsz) dec[rowo + v] = bd[n]; }
    }
    return;
  }

  float acc[8][7];
  #pragma unroll
  for (int j = 0; j < 8; ++j)
    #pragma unroll
    for (int n = 0; n < 7; ++n) acc[j][n] = 0.f;

  for (int kt = 0; kt < 16; ++kt) {
    int k0 = kt * 64;
    {   // stage A transposed: Al[k][m]
      int m = tid >> 1;
      int kh = (tid & 1) * 32;
      const float* src = outp + ((size_t)b * Tsz + t0 + m) * Hsz + k0 + kh;
      #pragma unroll
      for (int i = 0; i < 32; i += 4) {
        f32x4 v = *(const f32x4*)(src + i);
        Al[(kh + i + 0) * 132 + m] = v[0];
        Al[(kh + i + 1) * 132 + m] = v[1];
        Al[(kh + i + 2) * 132 + m] = v[2];
        Al[(kh + i + 3) * 132 + m] = v[3];
      }
    }
    {   // stage B
      const f32x4* s = (const f32x4*)(WdecT + (size_t)k0 * 112);
      f32x4* d4 = (f32x4*)Bl;
      for (int i = tid; i < 1792; i += 256) d4[i] = s[i];
    }
    __syncthreads();
    #pragma unroll 4
    for (int i = 0; i < 64; ++i) {
      float a[8], bv[7];
      #pragma unroll
      for (int j = 0; j < 8; ++j) a[j] = Al[i * 132 + ty + 16 * j];
      #pragma unroll
      for (int n = 0; n < 7; ++n) bv[n] = Bl[i * 112 + tx + 16 * n];
      #pragma unroll
      for (int j = 0; j < 8; ++j)
        #pragma unroll
        for (int n = 0; n < 7; ++n) acc[j][n] += a[j] * bv[n];
    }
    __syncthreads();
  }
  #pragma unroll
  for (int j = 0; j < 8; ++j) {
    int m = ty + 16 * j;
    size_t rowo = ((size_t)b * Tsz + t0 + m) * (size_t)Vsz;
    #pragma unroll
    for (int n = 0; n < 7; ++n) {
      int v = tx + 16 * n;
      if (v < Vsz) dec[rowo + v] = acc[j][n] + bd[n];
    }
  }
}

extern "C" void kernel_launch(void* const* d_in, const int* in_sizes, int n_in,
                              void* d_out, int out_size, void* d_ws, size_t ws_size,
                              hipStream_t stream) {
  const int*   chars = (const int*)d_in[0];
  const int*   lens  = (const int*)d_in[1];
  const float* emb   = (const float*)d_in[2];
  const float* Wih   = (const float*)d_in[3];
  const float* Whh   = (const float*)d_in[4];
  const float* bih   = (const float*)d_in[5];
  const float* bhh   = (const float*)d_in[6];
  const float* Wdec  = (const float*)d_in[7];
  const float* bdec  = (const float*)d_in[8];
  float* dout = (float*)d_out;
  char* ws = (char*)d_ws;
  float*          table = (float*)ws;                       // 1,638,400 B
  float*          WdecT = (float*)(ws + 1638400);           //   458,752 B
  unsigned short* hbf   = (unsigned short*)(ws + 2097152);  //   262,144 B
  int*            flags = (int*)(ws + 2359296);             //     2,048 B

  k_table<<<16, 256, 0, stream>>>(emb, Wih, bih, bhh, table);
  k_wdecT<<<448, 256, 0, stream>>>(Wdec, WdecT, flags);      // also zeroes flags
  k_zero_tail<<<64, 256, 0, stream>>>(lens, dout);
  k_lstm<<<256, 256, 0, stream>>>(chars, lens, Whh, table, hbf, flags, dout);
  k_decode<<<512, 256, 0, stream>>>(dout, WdecT, lens, bdec, dout + 67239936);
}